// Round 8
// baseline (213.417 us; speedup 1.0000x reference)
//
#include <hip/hip_runtime.h>
#include <math.h>

#define T_  2048
#define C_  1024
#define HD_ 64

typedef __attribute__((ext_vector_type(8))) short bf16x8;   // 8 bf16 = 4 VGPRs
typedef __attribute__((ext_vector_type(4))) float f32x4;    // MFMA C/D

#define MFMA_BF16(A, B, C) __builtin_amdgcn_mfma_f32_16x16x32_bf16(A, B, C, 0, 0, 0)

// Intra-wave LDS ordering fence (DS ops only — does NOT drain vmcnt, so
// global-load prefetch stays in flight across it).
#define WAVE_LDS_FENCE() do {                                   \
    __builtin_amdgcn_wave_barrier();                            \
    __asm__ volatile("s_waitcnt lgkmcnt(0)" ::: "memory");      \
    __builtin_amdgcn_wave_barrier();                            \
} while (0)

__device__ __forceinline__ short f2bf(float f) {
    union { float f; unsigned u; } v; v.f = f;
    unsigned r = v.u + 0x7fffu + ((v.u >> 16) & 1u);   // RTNE
    return (short)(r >> 16);
}
__device__ __forceinline__ float bf2f(short s) {
    union { float f; unsigned u; } v;
    v.u = ((unsigned)(unsigned short)s) << 16;
    return v.f;
}

// ---------------------------------------------------------------------------
// K0: W[1024][64] fp32 -> wt[m][pl][64 h][1024 c] bf16 hi/lo (transposed).
// ---------------------------------------------------------------------------
__global__ __launch_bounds__(256) void prep_w_kernel(
    const float* __restrict__ Wq, const float* __restrict__ Wk,
    const float* __restrict__ Wv, short* __restrict__ wt)
{
    __shared__ __align__(16) short hi_l[64 * 72], lo_l[64 * 72];
    const int m = blockIdx.y;
    const float* W = (m == 0) ? Wq : (m == 1) ? Wk : Wv;
    const int t = threadIdx.x;
    const int C0 = blockIdx.x * 64;
    {
        const int c = t >> 2, hq = t & 3;
        const float4* wp = (const float4*)(W + (size_t)(C0 + c) * HD_ + hq * 16);
        #pragma unroll
        for (int u = 0; u < 4; ++u) {
            float4 f = wp[u];
            float vs[4] = {f.x, f.y, f.z, f.w};
            #pragma unroll
            for (int e = 0; e < 4; ++e) {
                int h = hq * 16 + u * 4 + e;
                short hh = f2bf(vs[e]);
                hi_l[h * 72 + c] = hh;
                lo_l[h * 72 + c] = f2bf(vs[e] - bf2f(hh));
            }
        }
    }
    __syncthreads();
    {
        const int h = t >> 2, cc = (t & 3) * 16;
        short* dh = wt + (size_t)(m * 2 + 0) * 65536 + h * 1024 + C0 + cc;
        short* dl = wt + (size_t)(m * 2 + 1) * 65536 + h * 1024 + C0 + cc;
        *(bf16x8*)dh       = *(const bf16x8*)&hi_l[h * 72 + cc];
        *(bf16x8*)(dh + 8) = *(const bf16x8*)&hi_l[h * 72 + cc + 8];
        *(bf16x8*)dl       = *(const bf16x8*)&lo_l[h * 72 + cc];
        *(bf16x8*)(dl + 8) = *(const bf16x8*)&lo_l[h * 72 + cc + 8];
    }
}

// ---------------------------------------------------------------------------
// K1: QKV projection. Block = 16 rows, 512 thr = 8 waves = (kq2 x colq4):
// k-split over C halves -> grid 512 = 2 blocks/CU = 16 waves/CU, 16-iter
// chains, depth-2 register prefetch. One barrier (12 KB LDS kq-reduce).
// ---------------------------------------------------------------------------
__global__ __launch_bounds__(512, 4) void qkv_proj_kernel(
    const float* __restrict__ x, const short* __restrict__ wt,
    short* __restrict__ qhp, short* __restrict__ qlp,
    short* __restrict__ khp, short* __restrict__ klp,
    short* __restrict__ vtp)
{
    __shared__ float pbuf[4][64][12];   // 12 KB

    const int t = threadIdx.x, L = t & 63, wv = t >> 6;
    const int kq = wv & 1, colq = wv >> 1;
    const int R0 = blockIdx.x * 16;
    const int h = colq * 16 + (L & 15);
    const int quad = L >> 4;

    f32x4 aq = {0.f, 0.f, 0.f, 0.f};
    f32x4 ak = {0.f, 0.f, 0.f, 0.f};
    f32x4 av = {0.f, 0.f, 0.f, 0.f};

    const int cb = kq * 512 + quad * 8;
    const float* xp  = x + (size_t)(R0 + (L & 15)) * C_ + cb;
    const short* wqh = wt + (size_t)0 * 65536 + h * 1024 + cb;
    const short* wql = wt + (size_t)1 * 65536 + h * 1024 + cb;
    const short* wkh = wt + (size_t)2 * 65536 + h * 1024 + cb;
    const short* wkl = wt + (size_t)3 * 65536 + h * 1024 + cb;
    const short* wvh = wt + (size_t)4 * 65536 + h * 1024 + cb;

    float4 xA[2], xB[2];
    bf16x8 wb[2][5];
    auto ld = [&](int it, int s) {
        const int c0 = it * 32;
        xA[s] = *(const float4*)(xp + c0);
        xB[s] = *(const float4*)(xp + c0 + 4);
        wb[s][0] = *(const bf16x8*)(wqh + c0);
        wb[s][1] = *(const bf16x8*)(wql + c0);
        wb[s][2] = *(const bf16x8*)(wkh + c0);
        wb[s][3] = *(const bf16x8*)(wkl + c0);
        wb[s][4] = *(const bf16x8*)(wvh + c0);
    };

    ld(0, 0);
    for (int it = 0; it < 16; ++it) {          // 16 x 32 = 512 = this kq half
        const int s = it & 1;
        if (it + 1 < 16) ld(it + 1, s ^ 1);
        float vs[8] = {xA[s].x, xA[s].y, xA[s].z, xA[s].w,
                       xB[s].x, xB[s].y, xB[s].z, xB[s].w};
        bf16x8 axh, axl;
        #pragma unroll
        for (int e = 0; e < 8; ++e) {
            short hh = f2bf(vs[e]);
            axh[e] = hh;
            axl[e] = f2bf(vs[e] - bf2f(hh));
        }
        aq = MFMA_BF16(axl, wb[s][0], aq);
        aq = MFMA_BF16(axh, wb[s][1], aq);
        aq = MFMA_BF16(axh, wb[s][0], aq);
        ak = MFMA_BF16(axl, wb[s][2], ak);
        ak = MFMA_BF16(axh, wb[s][3], ak);
        ak = MFMA_BF16(axh, wb[s][2], ak);
        av = MFMA_BF16(wb[s][4], axh, av);     // swapped -> D[h][t]
    }

    if (kq == 1) {
        float* pb = &pbuf[colq][L][0];
        *(f32x4*)&pb[0] = aq;
        *(f32x4*)&pb[4] = ak;
        *(f32x4*)&pb[8] = av;
    }
    __syncthreads();
    if (kq == 0) {
        const float* pb = &pbuf[colq][L][0];
        aq += *(const f32x4*)&pb[0];
        ak += *(const f32x4*)&pb[4];
        av += *(const f32x4*)&pb[8];
        #pragma unroll
        for (int r = 0; r < 4; ++r) {
            int row = R0 + quad * 4 + r;
            float vq = aq[r] * 8.f;            // fold sqrt(HD)=8 into q
            short hq2 = f2bf(vq);
            qhp[(size_t)row * HD_ + h] = hq2;
            qlp[(size_t)row * HD_ + h] = f2bf(vq - bf2f(hq2));
            float vk = ak[r];
            short hk2 = f2bf(vk);
            khp[(size_t)row * HD_ + h] = hk2;
            klp[(size_t)row * HD_ + h] = f2bf(vk - bf2f(hk2));
            int d = colq * 16 + quad * 4 + r;
            int tt = R0 + (L & 15);
            int bb = tt >> 11, tl = tt & (T_ - 1);
            vtp[(size_t)(bb * 64 + d) * T_ + tl] = f2bf(av[r]);
        }
    }
}

// ---------------------------------------------------------------------------
// K2: full-row softmax stats. grid 512 x 256 thr. Block = 16 rows; wave =
// 512-col segment, processed as 4 batches of 8 INDEPENDENT col-tiles
// (32 loads + 48 MFMAs in flight per batch), deferred-max fold per batch.
// ---------------------------------------------------------------------------
__global__ __launch_bounds__(256, 2) void stats_kernel(
    const short* __restrict__ qhp, const short* __restrict__ qlp,
    const short* __restrict__ khp, const short* __restrict__ klp,
    float* __restrict__ msp, float* __restrict__ ilp)
{
    __shared__ float statb[4][16][2];

    const int t = threadIdx.x, L = t & 63, wv = t >> 6;   // wv 0..3
    const int quad = L >> 4;
    const int R0 = blockIdx.x * 16;
    const int b = R0 >> 11;

    bf16x8 qfh[2], qfl[2];
    {
        int row = R0 + (L & 15);
        #pragma unroll
        for (int dc = 0; dc < 2; ++dc) {
            size_t off = (size_t)row * HD_ + dc * 32 + quad * 8;
            qfh[dc] = *(const bf16x8*)(qhp + off);
            qfl[dc] = *(const bf16x8*)(qlp + off);
        }
    }

    float M[4], S[4];
    #pragma unroll
    for (int r = 0; r < 4; ++r) { M[r] = -3e38f; S[r] = 0.f; }

    for (int batch = 0; batch < 4; ++batch) {
        f32x4 sb[8];
        #pragma unroll
        for (int u = 0; u < 8; ++u) {
            int gcol = (b << 11) + wv * 512 + (batch * 8 + u) * 16 + (L & 15);
            const short* kb  = khp + (size_t)gcol * HD_ + quad * 8;
            const short* kb2 = klp + (size_t)gcol * HD_ + quad * 8;
            bf16x8 kf0 = *(const bf16x8*)kb;
            bf16x8 kf1 = *(const bf16x8*)(kb + 32);
            bf16x8 kl0 = *(const bf16x8*)kb2;
            bf16x8 kl1 = *(const bf16x8*)(kb2 + 32);
            f32x4 s = {0.f, 0.f, 0.f, 0.f};
            s = MFMA_BF16(qfl[0], kf0, s);
            s = MFMA_BF16(qfh[0], kl0, s);
            s = MFMA_BF16(qfh[0], kf0, s);
            s = MFMA_BF16(qfl[1], kf1, s);
            s = MFMA_BF16(qfh[1], kl1, s);
            s = MFMA_BF16(qfh[1], kf1, s);
            sb[u] = s;
        }
        #pragma unroll
        for (int r = 0; r < 4; ++r) {
            float mc = sb[0][r];
            #pragma unroll
            for (int u = 1; u < 8; ++u) mc = fmaxf(mc, sb[u][r]);
            float lc = 0.f;
            #pragma unroll
            for (int u = 0; u < 8; ++u) lc += __expf(sb[u][r] - mc);
            float mn = fmaxf(M[r], mc);
            S[r] = S[r] * __expf(M[r] - mn) + lc * __expf(mc - mn);
            M[r] = mn;
        }
    }
    #pragma unroll
    for (int off = 1; off < 16; off <<= 1)
        #pragma unroll
        for (int r = 0; r < 4; ++r) {
            float mo = __shfl_xor(M[r], off, 64);
            float lo = __shfl_xor(S[r], off, 64);
            float mn = fmaxf(M[r], mo);
            S[r] = S[r] * __expf(M[r] - mn) + lo * __expf(mo - mn);
            M[r] = mn;
        }
    if ((L & 15) == 0) {
        #pragma unroll
        for (int r = 0; r < 4; ++r) {
            statb[wv][quad * 4 + r][0] = M[r];
            statb[wv][quad * 4 + r][1] = S[r];
        }
    }
    __syncthreads();
    if (t < 16) {
        float Mm = statb[0][t][0], Ss = statb[0][t][1];
        #pragma unroll
        for (int w = 1; w < 4; ++w) {
            float mo = statb[w][t][0], lo = statb[w][t][1];
            float mn = fmaxf(Mm, mo);
            Ss = Ss * __expf(Mm - mn) + lo * __expf(mo - mn);
            Mm = mn;
        }
        msp[R0 + t] = Mm;
        ilp[R0 + t] = 1.f / Ss;
    }
}

// ---------------------------------------------------------------------------
// K3: causal second softmax + PV. grid 512 x 256 thr (4 waves, jt stride 4,
// balanced pairing). Flattened (jt,ch) pipeline with double-buffered K
// prefetch; V loads issued before the es fence (hidden behind S+exp).
// Wave-private es slab + WAVE_LDS_FENCE; 2 block barriers total.
// ---------------------------------------------------------------------------
__global__ __launch_bounds__(256, 3) void pv_kernel(
    const short* __restrict__ qhp, const short* __restrict__ qlp,
    const short* __restrict__ khp, const short* __restrict__ klp,
    const short* __restrict__ vtp, const float* __restrict__ msp,
    const float* __restrict__ ilp, float* __restrict__ out)
{
    __shared__ __align__(16) float es32[4][16][36];  // 9.2 KB per-wave slabs
    __shared__ float obuf[4][16][68];                // 17.4 KB
    __shared__ float denb[4][16];
    __shared__ float dinv[16];

    const int t = threadIdx.x, L = t & 63, wv = t >> 6;   // wv 0..3
    const int quad = L >> 4;
    const int g = blockIdx.x;
    const int slot = g & 255, rnd = g >> 8;
    const int b = slot & 3, j = slot >> 2;
    const int p = rnd ? (127 - j) : j;       // balanced causal pairing
    const int IA = p * 16;
    const int nT = (p >> 3) + 1;             // causal 128-col tiles

    // q fragments (A-layout)
    bf16x8 qfh[2], qfl[2];
    {
        size_t base = ((size_t)(b << 11) + IA + (L & 15)) * HD_;
        #pragma unroll
        for (int dc = 0; dc < 2; ++dc) {
            qfh[dc] = *(const bf16x8*)(qhp + base + dc * 32 + quad * 8);
            qfl[dc] = *(const bf16x8*)(qlp + base + dc * 32 + quad * 8);
        }
    }
    float ms[4], il[4];
    #pragma unroll
    for (int r = 0; r < 4; ++r) {
        int gr = (b << 11) + IA + quad * 4 + r;
        ms[r] = msp[gr];
        il[r] = ilp[gr];
    }

    f32x4 ov[4];
    #pragma unroll
    for (int dt = 0; dt < 4; ++dt) ov[dt] = {0.f, 0.f, 0.f, 0.f};
    float den[4] = {0.f, 0.f, 0.f, 0.f};
    float* myes = &es32[wv][0][0];

    // wave's steps: jt = wv, wv+4, ... ; 4 ch per jt
    const int njt = (nT > wv) ? ((nT - wv - 1) / 4 + 1) : 0;
    const int nsteps = njt * 4;

    bf16x8 kb[2][8];       // [buf][cg2*4 + {kf0,kf1,kl0,kl1}]
    auto loadK = [&](int st, int buf) {
        const int jt = wv + (st >> 2) * 4, ch = st & 3;
        #pragma unroll
        for (int cg2 = 0; cg2 < 2; ++cg2) {
            const int gcol = (b << 11) + jt * 128 + ch * 32 + cg2 * 16 + (L & 15);
            const short* kh8 = khp + (size_t)gcol * HD_ + quad * 8;
            const short* kl8 = klp + (size_t)gcol * HD_ + quad * 8;
            kb[buf][cg2 * 4 + 0] = *(const bf16x8*)kh8;
            kb[buf][cg2 * 4 + 1] = *(const bf16x8*)(kh8 + 32);
            kb[buf][cg2 * 4 + 2] = *(const bf16x8*)kl8;
            kb[buf][cg2 * 4 + 3] = *(const bf16x8*)(kl8 + 32);
        }
    };

    if (nsteps > 0) loadK(0, 0);
    for (int st = 0; st < nsteps; ++st) {
        const int cb2 = st & 1;
        if (st + 1 < nsteps) loadK(st + 1, cb2 ^ 1);
        const int jt = wv + (st >> 2) * 4, ch = st & 3;
        // ---- S + second softmax e
        #pragma unroll
        for (int cg2 = 0; cg2 < 2; ++cg2) {
            f32x4 s = {0.f, 0.f, 0.f, 0.f};
            s = MFMA_BF16(qfl[0], kb[cb2][cg2 * 4 + 0], s);
            s = MFMA_BF16(qfh[0], kb[cb2][cg2 * 4 + 2], s);
            s = MFMA_BF16(qfh[0], kb[cb2][cg2 * 4 + 0], s);
            s = MFMA_BF16(qfl[1], kb[cb2][cg2 * 4 + 1], s);
            s = MFMA_BF16(qfh[1], kb[cb2][cg2 * 4 + 3], s);
            s = MFMA_BF16(qfh[1], kb[cb2][cg2 * 4 + 1], s);
            const int colg = jt * 128 + ch * 32 + cg2 * 16 + (L & 15);
            #pragma unroll
            for (int r = 0; r < 4; ++r) {
                float pvv = __expf(s[r] - ms[r]) * il[r];
                float ev = (colg <= IA + quad * 4 + r) ? __expf(pvv) : 0.f;
                den[r] += ev;
                myes[(quad * 4 + r) * 36 + cg2 * 16 + (L & 15)] = ev;
            }
        }
        // ---- V loads issued now (vmcnt), consumed after the fence
        bf16x8 vf[4];
        #pragma unroll
        for (int dt = 0; dt < 4; ++dt) {
            const int d = dt * 16 + (L & 15);
            vf[dt] = *(const bf16x8*)(vtp + ((size_t)(b * 64 + d) << 11)
                                      + jt * 128 + ch * 32 + quad * 8);
        }
        // ---- intra-wave C->A transform, fenced (DS only)
        WAVE_LDS_FENCE();
        const float* ep = &myes[(L & 15) * 36 + quad * 8];
        float4 e0 = *(const float4*)ep;
        float4 e1 = *(const float4*)(ep + 4);
        WAVE_LDS_FENCE();
        bf16x8 ef;
        ef[0] = f2bf(e0.x); ef[1] = f2bf(e0.y);
        ef[2] = f2bf(e0.z); ef[3] = f2bf(e0.w);
        ef[4] = f2bf(e1.x); ef[5] = f2bf(e1.y);
        ef[6] = f2bf(e1.z); ef[7] = f2bf(e1.w);
        #pragma unroll
        for (int dt = 0; dt < 4; ++dt)
            ov[dt] = MFMA_BF16(ef, vf[dt], ov[dt]);
    }

    // ---- den reduce + O cross-wave reduce
    #pragma unroll
    for (int off = 1; off < 16; off <<= 1)
        #pragma unroll
        for (int r = 0; r < 4; ++r)
            den[r] += __shfl_xor(den[r], off, 64);
    if ((L & 15) == 0) {
        #pragma unroll
        for (int r = 0; r < 4; ++r)
            denb[wv][quad * 4 + r] = den[r];
    }
    #pragma unroll
    for (int dt = 0; dt < 4; ++dt)
        #pragma unroll
        for (int r = 0; r < 4; ++r)
            obuf[wv][quad * 4 + r][dt * 16 + (L & 15)] = ov[dt][r];
    __syncthreads();
    if (t < 16) {
        float D = denb[0][t] + denb[1][t] + denb[2][t] + denb[3][t];
        dinv[t] = 1.f / D;
    }
    __syncthreads();
    #pragma unroll
    for (int u = 0; u < 4; ++u) {
        int idx = t + u * 256;
        int row = idx >> 6, d = idx & 63;
        float o = obuf[0][row][d] + obuf[1][row][d]
                + obuf[2][row][d] + obuf[3][row][d];
        out[((size_t)(b << 11) + IA + row) * HD_ + d] = o * dinv[row];
    }
}

// ---------------------------------------------------------------------------
extern "C" void kernel_launch(void* const* d_in, const int* in_sizes, int n_in,
                              void* d_out, int out_size, void* d_ws, size_t ws_size,
                              hipStream_t stream) {
    (void)in_sizes; (void)n_in; (void)out_size; (void)ws_size;
    const float* x  = (const float*)d_in[0];
    const float* Wq = (const float*)d_in[1];
    const float* Wk = (const float*)d_in[2];
    const float* Wv = (const float*)d_in[3];
    float* outp = (float*)d_out;

    char* ws = (char*)d_ws;                       // 5.75 MB used (proven size)
    short* wt  = (short*)ws;                      // 768 KB (dead after proj)
    float* msp = (float*)ws;                      // 32 KB (overlays wt post-proj)
    float* ilp = (float*)(ws + 32768);            // 32 KB
    short* qh = (short*)(ws + 786432);
    short* ql = (short*)(ws + 786432 + 1048576);
    short* kh = (short*)(ws + 786432 + 2 * 1048576);
    short* kl = (short*)(ws + 786432 + 3 * 1048576);
    short* vt = (short*)(ws + 786432 + 4 * 1048576);  // [4][64][2048] bf16

    prep_w_kernel<<<dim3(16, 3), 256, 0, stream>>>(Wq, Wk, Wv, wt);
    qkv_proj_kernel<<<dim3(512), 512, 0, stream>>>(x, wt, qh, ql, kh, kl, vt);
    stats_kernel<<<dim3(512), 256, 0, stream>>>(qh, ql, kh, kl, msp, ilp);
    pv_kernel<<<dim3(512), 256, 0, stream>>>(qh, ql, kh, kl, vt, msp, ilp, outp);
}